// Round 3
// baseline (182.834 us; speedup 1.0000x reference)
//
#include <hip/hip_runtime.h>

#define BB 256
#define LL 512

typedef float nfloat4 __attribute__((ext_vector_type(4)));
typedef int   nint4   __attribute__((ext_vector_type(4)));

// ---------------------------------------------------------------------------
// One block per BATCH (512 threads, 8 waves), both dirs merged:
//   shared prefix ONCE: packed histogram -> distinct-count rank map (<=63) ->
//   canonical pair insert into two direct maps (dmapS: src-side mult,
//   dmapD: dst-side mult; pair key = rank-pair < 4096) -> one compaction
//   produces keyS/multS + keyD/multD, which serve BOTH dirs:
//     dir0: A-phase (context=dst) over keyD, B-phase (x=src) over keyS
//     dir1: A-phase over keyS,              B-phase over keyD
//   Position->row indices for both dirs packed into one pidxl word.
// Then serialized A0,B0,A1,B1 with all 8 waves each; single Mg (stride 68);
// encode table (tabL) shared across everything. Static LDS 62.8 KB.
// ---------------------------------------------------------------------------
__global__ __launch_bounds__(512, 2) void k_all(
    const int* __restrict__ src, const int* __restrict__ dst,
    const float* __restrict__ w1, const float* __restrict__ b1,
    const float* __restrict__ w2, const float* __restrict__ b2,
    const float* __restrict__ Wq, const float* __restrict__ Wk,
    const float* __restrict__ Wv, const float* __restrict__ Wo,
    const float* __restrict__ bo, const float* __restrict__ lng,
    const float* __restrict__ lnb, float* __restrict__ out) {
  // ---- LDS layout (byte offsets; regions reused across phases) ----
  // [0,16384)      dmapS (4096 int) -> tabL 64x64 f
  // [16384,33792)  dmapD (first 16384) -> Mg: MT 64 x stride-68 f (17408)
  // [33792,46080)  pool 12288: hist(2000 int) -> pA/vA (24x64 x2 f) ->
  //                Phase B row staging (32x64 f)
  // [46080,54272)  keyS | multS | keyD | multD (512 ints each)
  // [54272,56320)  pidxl (512 ints, dir0 idx lo16 | dir1 idx hi16)
  // [56320,60416)  fbF: featb/tbuf (512 f) | qbuf/sred (512 f)
  // [60416,62468)  cflag(513) -> cmap
  // [62468,62724)  clist(64)
  // [62724,62740)  npp[4]: [0]=nS [1]=nD [2]=nc
  __shared__ __align__(16) char smem[62752];
  int*   dmapS = (int*)smem;
  float* tabL  = (float*)smem;
  int*   dmapD = (int*)(smem + 16384);
  float* Mg    = (float*)(smem + 16384);   // stride 68
  int*   histp = (int*)(smem + 33792);     // packed: src cnt lo16 | dst hi16
  float* poolF = (float*)(smem + 33792);
  int*   keyS  = (int*)(smem + 46080);
  int*   multS = (int*)(smem + 48128);
  int*   keyD  = (int*)(smem + 50176);
  int*   multD = (int*)(smem + 52224);
  int*   pidxl = (int*)(smem + 54272);
  float* fbF   = (float*)(smem + 56320);   // featb 0..511 | qbuf 512..1023
  int*   cflag = (int*)(smem + 60416);
  int*   clist = (int*)(smem + 62468);
  int*   npp   = (int*)(smem + 62724);

  int b = blockIdx.x;
  int tid = threadIdx.x, tx = tid & 63, ty = tid >> 6;   // ty in 0..7

  // ---- phase 0: id loads + hoisted w2 column + vec4 zero ----
  const int* s = src + b * LL;
  const int* d = dst + b * LL;
  int sid = s[tid], did = d[tid];

  float wcA[64], wcB[64];
#pragma unroll
  for (int f = 0; f < 64; ++f) wcA[f] = w2[f * 64 + tx];
  float w1v = w1[tx], b1v = b1[tx], b2v = b2[tx];
  float bov = bo[tx], lg = lng[tx], lb = lnb[tx];

  {
    nint4 z4 = {0, 0, 0, 0};
    nint4* dm4 = (nint4*)smem;           // dmapS+dmapD contiguous: 8192 ints
    for (int i = tid; i < 2048; i += 512) dm4[i] = z4;
    nint4* h4z = (nint4*)histp;          // 2000 ints = 500 vec4
    if (tid < 500) h4z[tid] = z4;
    if (tid < 128) ((nint4*)cflag)[tid] = z4;
    if (tid == 0) cflag[512] = 0;
    if (tid < 4) npp[tid] = 0;
  }
  __syncthreads();

  // ---- packed histogram: both sides, once per batch ----
  atomicAdd(&histp[sid], 1);
  atomicAdd(&histp[did], 65536);
  __syncthreads();

  // ---- flag distinct count values (idempotent stores) ----
  for (int i = tid; i < 2000; i += 512) {
    int hv = histp[i];
    if (i != 0 && hv != 0) { cflag[hv & 0xffff] = 1; cflag[hv >> 16] = 1; }
  }
  if (tid == 0) cflag[0] = 1;            // id-0 pair is (0,0)
  __syncthreads();

  // ---- compact count values -> rank map (<= 63: 31+31+zero) ----
  for (int c = tid; c < 513; c += 512) {
    if (cflag[c]) { int idx = atomicAdd(&npp[2], 1); clist[idx] = c; cflag[c] = idx; }
  }
  __syncthreads();

  // ---- canonical pair insert: one scan serves both dirs ----
  for (int i = tid; i < 2000; i += 512) {
    int hv = histp[i];
    if (i == 0 || hv == 0) continue;
    int cs = hv & 0xffff, cd = hv >> 16;
    int k = cflag[min(cs, cd)] * 64 + cflag[max(cs, cd)];
    if (cs) atomicAdd(&dmapS[k], cs);
    if (cd) atomicAdd(&dmapD[k], cd);
  }
  if (tid == 0) {                        // id 0: appearances forced to (0,0)
    int hv = histp[0];
    int cs = hv & 0xffff, cd = hv >> 16;
    int k00 = cflag[0] * 65;
    if (cs) atomicAdd(&dmapS[k00], cs);
    if (cd) atomicAdd(&dmapD[k00], cd);
  }
  __syncthreads();

  // ---- single compaction pass: keyS/multS + keyD/multD for both dirs ----
  for (int i = tid; i < 4096; i += 512) {
    int vS = dmapS[i];
    if (vS) { int ix = atomicAdd(&npp[0], 1); keyS[ix] = i; multS[ix] = vS; dmapS[i] = ix; }
    int vD = dmapD[i];
    if (vD) { int ix = atomicAdd(&npp[1], 1); keyD[ix] = i; multD[ix] = vD; dmapD[i] = ix; }
  }
  __syncthreads();
  int nS = npp[0], nD = npp[1], nc = npp[2];

  // ---- pidxl gather: both dirs packed into one word ----
  {
    int k0, k1;
    if (sid == 0) k0 = cflag[0] * 65;
    else { int hv = histp[sid]; int cs = hv & 0xffff, cd = hv >> 16;
           k0 = cflag[min(cs, cd)] * 64 + cflag[max(cs, cd)]; }
    if (did == 0) k1 = cflag[0] * 65;
    else { int hv = histp[did]; int cs = hv & 0xffff, cd = hv >> 16;
           k1 = cflag[min(cs, cd)] * 64 + cflag[max(cs, cd)]; }
    pidxl[tid] = (dmapS[k0] & 0xffff) | (dmapD[k1] << 16);
  }
  __syncthreads();   // dmap reads complete before tabL overwrites the region

  // ---- encode table, once per batch: T(c)[g] ----
  for (int i = ty; i < nc; i += 8) {
    float c = (float)clist[i];
    fbF[ty * 64 + tx] = fmaxf(c * w1v + b1v, 0.f);       // wave-local h row
    float acc = b2v;
    const float4* h4p = (const float4*)&fbF[ty * 64];
#pragma unroll
    for (int q = 0; q < 16; ++q) {
      float4 hv = h4p[q];
      acc += hv.x * wcA[4*q] + hv.y * wcA[4*q+1] + hv.z * wcA[4*q+2] + hv.w * wcA[4*q+3];
    }
    tabL[i * 64 + tx] = acc;
  }
  // Wk / Wv columns for the first A-phase
#pragma unroll
  for (int f = 0; f < 64; ++f) { wcA[f] = Wk[f * 64 + tx]; wcB[f] = Wv[f * 64 + tx]; }
  __syncthreads();   // tabL ready

  for (int dir = 0; dir < 2; ++dir) {
    // ---- Phase A (dir): context rows; thread owns M[d=tx][e=ty*8..+7] ----
    const int* aKey = dir ? keyS : keyD;
    const int* aMul = dir ? multS : multD;
    int Pa = dir ? nS : nD;
    float macc[8];
#pragma unroll
    for (int e = 0; e < 8; ++e) macc[e] = 0.f;
    float sacc = 0.f;
    float* pA = poolF;           // 24 x 64
    float* vA = poolF + 1536;    // 24 x 64
    for (int j0 = 0; j0 < Pa; j0 += 24) {
      int cN = min(24, Pa - j0);
      for (int j = ty; j < cN; j += 8) {
        int key = aKey[j0 + j];
        int ia = key >> 6, ib = key & 63;
        fbF[ty * 64 + tx] = tabL[ia * 64 + tx] + tabL[ib * 64 + tx];
        float kr = 0.f, vr = 0.f;
        const float4* fb4 = (const float4*)&fbF[ty * 64];
#pragma unroll
        for (int q = 0; q < 16; ++q) {
          float4 fv = fb4[q];
          kr += fv.x * wcA[4*q] + fv.y * wcA[4*q+1] + fv.z * wcA[4*q+2] + fv.w * wcA[4*q+3];
          vr += fv.x * wcB[4*q] + fv.y * wcB[4*q+1] + fv.z * wcB[4*q+2] + fv.w * wcB[4*q+3];
        }
        float p = __expf(kr) * (float)aMul[j0 + j];
        sacc += p;
        pA[j * 64 + tx] = p;
        vA[j * 64 + tx] = vr;
      }
      if (j0 + 24 >= Pa) fbF[512 + ty * 64 + tx] = sacc;  // fold sacc barrier
      __syncthreads();
      for (int jj = 0; jj < cN; ++jj) {
        float pg = pA[jj * 64 + tx];
        const float4* vb4 = (const float4*)&vA[jj * 64 + ty * 8];
        float4 v0 = vb4[0], v1 = vb4[1];
        macc[0] += pg * v0.x; macc[1] += pg * v0.y;
        macc[2] += pg * v0.z; macc[3] += pg * v0.w;
        macc[4] += pg * v1.x; macc[5] += pg * v1.y;
        macc[6] += pg * v1.z; macc[7] += pg * v1.w;
      }
      __syncthreads();
    }
    float csum = 0.f;
#pragma unroll
    for (int w = 0; w < 8; ++w) csum += fbF[512 + w * 64 + tx];
    float inv = 1.f / csum;
#pragma unroll
    for (int e = 0; e < 8; ++e) Mg[(ty * 8 + e) * 68 + tx] = macc[e] * inv;
    // Wq + Wo columns for Phase B (wcA/wcB dead after A)
#pragma unroll
    for (int f = 0; f < 64; ++f) { wcA[f] = Wq[f * 64 + tx]; wcB[f] = Wo[f * 64 + tx]; }
    __syncthreads();   // Mg visible; pool free for staging

    // ---- Phase B (dir): at = (qh . M_hat) . Wo; chunked scatter ----
    const int* bKey = dir ? keyD : keyS;
    int Pb = dir ? nD : nS;
    for (int i0 = 0; i0 < Pb; i0 += 32) {
      int cN = min(32, Pb - i0);
      for (int jj = ty; jj < cN; jj += 8) {
        int key = bKey[i0 + jj];
        int ia = key >> 6, ib = key & 63;
        float fv = tabL[ia * 64 + tx] + tabL[ib * 64 + tx];
        fbF[ty * 64 + tx] = fv;
        float qr = 0.f;
        const float4* fb4 = (const float4*)&fbF[ty * 64];
#pragma unroll
        for (int q = 0; q < 16; ++q) {
          float4 f4v = fb4[q];
          qr += f4v.x * wcA[4*q] + f4v.y * wcA[4*q+1] + f4v.z * wcA[4*q+2] + f4v.w * wcA[4*q+3];
        }
        float p = __expf(qr);
        float sum = p;
#pragma unroll
        for (int off = 32; off >= 1; off >>= 1) sum += __shfl_xor(sum, off, 64);
        float qh = p / sum * 0.125f;   // softmax * F^-0.5
        fbF[512 + ty * 64 + tx] = qh;
        // stage 1: t[f=tx] = sum_d qh[d] * MT[tx][d]
        float t = 0.f;
        const float4* qb4 = (const float4*)&fbF[512 + ty * 64];
        const float4* mt4 = (const float4*)&Mg[tx * 68];
#pragma unroll
        for (int q = 0; q < 16; ++q) {
          float4 qv = qb4[q];
          float4 mv = mt4[q];
          t += qv.x * mv.x + qv.y * mv.y + qv.z * mv.z + qv.w * mv.w;
        }
        fbF[ty * 64 + tx] = t;   // featb slice dead (fv held in register)
        // stage 2: at[o=tx] = sum_f t[f] * Wo[f][tx]
        float at = 0.f;
        const float4* tb4 = (const float4*)&fbF[ty * 64];
#pragma unroll
        for (int q = 0; q < 16; ++q) {
          float4 tv = tb4[q];
          at += tv.x * wcB[4*q] + tv.y * wcB[4*q+1] + tv.z * wcB[4*q+2] + tv.w * wcB[4*q+3];
        }
        float r = fv + at + bov;
        float mu = r;
#pragma unroll
        for (int off = 32; off >= 1; off >>= 1) mu += __shfl_xor(mu, off, 64);
        mu *= (1.f / 64.f);
        float dv = r - mu;
        float var = dv * dv;
#pragma unroll
        for (int off = 32; off >= 1; off >>= 1) var += __shfl_xor(var, off, 64);
        var *= (1.f / 64.f);
        poolF[jj * 64 + tx] = dv * rsqrtf(var + 1e-5f) * lg + lb;
      }
      __syncthreads();
      const nfloat4* w4 = (const nfloat4*)poolF;
      nfloat4* out4 = (nfloat4*)(out + (size_t)(dir * BB + b) * (LL * 64));
      for (int idx = tid; idx < 512 * 16; idx += 512) {
        int l = idx >> 4, q = idx & 15;
        int pw = pidxl[l];
        int pid = dir ? (pw >> 16) : (pw & 0xffff);
        if (pid >= i0 && pid < i0 + cN)
          __builtin_nontemporal_store(w4[(pid - i0) * 16 + q], &out4[l * 16 + q]);
      }
      __syncthreads();
    }
    if (dir == 0) {   // reload Wk / Wv for the second A-phase (register-only)
#pragma unroll
      for (int f = 0; f < 64; ++f) { wcA[f] = Wk[f * 64 + tx]; wcB[f] = Wv[f * 64 + tx]; }
    }
  }
}

extern "C" void kernel_launch(void* const* d_in, const int* in_sizes, int n_in,
                              void* d_out, int out_size, void* d_ws, size_t ws_size,
                              hipStream_t stream) {
  const int* src  = (const int*)d_in[0];
  const int* dst  = (const int*)d_in[1];
  const float* w1 = (const float*)d_in[2];
  const float* b1 = (const float*)d_in[3];
  const float* w2 = (const float*)d_in[4];
  const float* b2 = (const float*)d_in[5];
  const float* Wq = (const float*)d_in[6];
  const float* Wk = (const float*)d_in[7];
  const float* Wv = (const float*)d_in[8];
  const float* Wo = (const float*)d_in[9];
  const float* bo = (const float*)d_in[10];
  const float* lng = (const float*)d_in[11];
  const float* lnb = (const float*)d_in[12];
  float* out = (float*)d_out;

  k_all<<<dim3(BB), dim3(512), 0, stream>>>(src, dst, w1, b1, w2, b2,
                                            Wq, Wk, Wv, Wo, bo, lng, lnb, out);
}

// Round 4
// 116.639 us; speedup vs baseline: 1.5675x; 1.5675x over previous
//
#include <hip/hip_runtime.h>

#define BB 256
#define LL 512

typedef float nfloat4 __attribute__((ext_vector_type(4)));
typedef int   nint4   __attribute__((ext_vector_type(4)));

// ---------------------------------------------------------------------------
// Single fused kernel per (batch, dir)  [revert to best-measured structure]:
//   packed histograms -> merged pair dedup (1 hash pass, side-tagged keys) ->
//   per-block encode table (distinct count values only; provably <= 63 rows)
//   -> linear cross-attn on deduped rows -> LN -> scatter to 512 positions.
// Phase B computes at = (qh . M_hat) . Wo via two broadcast-dots (no G phase).
// 256 threads + __launch_bounds__(256,2): weight columns (wcA/wcB, 128 VGPRs)
// stay register-resident -- the 512-thread variant spilled to scratch
// (VGPR_Count=128, 85 MB FETCH of spill traffic, 3x slowdown). Do not widen.
// Only change vs the 117.9 us version: vec4 LDS zero-init.
// ---------------------------------------------------------------------------
__global__ __launch_bounds__(256, 2) void k_all(
    const int* __restrict__ src, const int* __restrict__ dst,
    const float* __restrict__ w1, const float* __restrict__ b1,
    const float* __restrict__ w2, const float* __restrict__ b2,
    const float* __restrict__ Wq, const float* __restrict__ Wk,
    const float* __restrict__ Wv, const float* __restrict__ Wo,
    const float* __restrict__ bo, const float* __restrict__ lng,
    const float* __restrict__ lnb, float* __restrict__ out) {
  // ---- LDS layout (byte offsets; regions reused across phases) ----
  // [0,16384)      hist(2000 int packed) -> Phase A pA/vA (2x32x64 f) ->
  //                Phase B row chunk (64x64 f)
  // [16384,32768)  hkey(1024)+hmult(1024) -> tabL 64x64 f
  // [32768,50176)  Mg: MT (64 x stride-68 f), alive through Phase B
  // [50176,58368)  xkey | ckey | cmult | pidxl (512 ints each)
  // [58368,60680)  cflag(513) + clist(64)
  // [60688,63760)  fbF: featb | qbuf | sred/tbuf (256 f each)
  // [63760,63772)  npp[3]
  __shared__ __align__(16) char smem[63776];
  int*   hist  = (int*)smem;               // 2000 ints: src cnt lo16, dst hi16
  float* poolF = (float*)smem;
  int*   hkey  = (int*)(smem + 16384);
  int*   hmult = (int*)(smem + 20480);
  float* tabL  = (float*)(smem + 16384);   // 64 rows x 64
  float* Mg    = (float*)(smem + 32768);   // MT, stride 68
  int*   xkey  = (int*)(smem + 50176);
  int*   ckey  = (int*)(smem + 52224);
  int*   cmult = (int*)(smem + 54272);
  int*   pidxl = (int*)(smem + 56320);
  int*   cflag = (int*)(smem + 58368);     // 513 ints -> becomes cmap
  int*   clist = (int*)(smem + 60424);     // 64 ints
  float* fbF   = (float*)(smem + 60688);   // featb 0..255|qbuf 256..511|sred 512..767
  int*   npp   = (int*)(smem + 63760);     // [0]=Pc [1]=Px [2]=nc

  int bd = blockIdx.x, b = bd >> 1, dir = bd & 1;
  int tid = threadIdx.x, tx = tid & 63, ty = tid >> 6;
  int e0 = ty * 16;

  // ---- phase 0: id loads + hoisted w2-column loads + vec4 zero ----
  const int* s = src + b * LL;
  const int* d = dst + b * LL;
  int sid0 = s[tid], sid1 = s[tid + 256];
  int did0 = d[tid], did1 = d[tid + 256];

  // hoist encode-MLP weight loads: latency hides under hist/dedup phases
  float wcA[64], wcB[64];
#pragma unroll
  for (int f = 0; f < 64; ++f) wcA[f] = w2[f * 64 + tx];   // w2 column tx
  float w1v = w1[tx], b1v = b1[tx], b2v = b2[tx];

  {
    nint4 z4 = {0, 0, 0, 0};
    nint4 m4 = {-1, -1, -1, -1};
    nint4* h4z = (nint4*)hist;           // 2000 ints = 500 vec4
    for (int i = tid; i < 500; i += 256) h4z[i] = z4;
    ((nint4*)hkey)[tid]  = m4;           // 1024 ints = 256 vec4
    ((nint4*)hmult)[tid] = z4;           // 1024 ints = 256 vec4
    if (tid < 128) ((nint4*)cflag)[tid] = z4;   // 512 ints
    if (tid == 0) cflag[512] = 0;
    if (tid < 3) npp[tid] = 0;
  }
  __syncthreads();

  // ---- packed histograms: one word per id, both sides ----
  atomicAdd(&hist[sid0], 1);      atomicAdd(&hist[sid1], 1);
  atomicAdd(&hist[did0], 65536);  atomicAdd(&hist[did1], 65536);
  __syncthreads();

  int x0 = dir ? did0 : sid0, x1 = dir ? did1 : sid1;
  int c0 = dir ? sid0 : did0, c1 = dir ? sid1 : did1;

  // ---- merged dedup insert: 2 c-side + 2 x-side keys per thread ----
  // key components: ca = count of id in its OWN list, cb = other list.
  // own list is src  <=>  side != dir.
  int slot0 = 0, slot1 = 0;
#pragma unroll
  for (int r = 0; r < 4; ++r) {
    int side = r >> 1;   // 0 = context side, 1 = x side
    int id = (r == 0) ? c0 : (r == 1) ? c1 : (r == 2) ? x0 : x1;
    int ca = 0, cb = 0;
    if (id != 0) {
      int hv = hist[id];
      int cs = hv & 0xffff, cd2 = hv >> 16;
      if (side != dir) { ca = cs; cb = cd2; }
      else             { ca = cd2; cb = cs; }
    }
    int key = ca | (cb << 10) | (side << 20);
    int h = (int)(((unsigned)key * 2654435761u) >> 22) & 1023;
    while (true) {
      int old = atomicCAS(&hkey[h], -1, key);
      if (old == -1 || old == key) break;
      h = (h + 1) & 1023;
    }
    if (side == 0) atomicAdd(&hmult[h], 1);
    else if (r == 2) slot0 = h;
    else slot1 = h;
  }
  __syncthreads();

  // ---- compaction: one scan serves both sides ----
  for (int i = tid; i < 1024; i += 256) {
    int k = hkey[i];
    if (k != -1) {
      if (k & (1 << 20)) {
        int idx = atomicAdd(&npp[1], 1);
        xkey[idx] = k & 0xFFFFF;
        hkey[i] = idx;            // slot -> compacted x index
      } else {
        int idx = atomicAdd(&npp[0], 1);
        ckey[idx]  = k;
        cmult[idx] = hmult[i];
      }
    }
  }
  __syncthreads();
  int Pc = npp[0], Px = npp[1];
  pidxl[tid]       = hkey[slot0];
  pidxl[tid + 256] = hkey[slot1];
  // mark distinct count values (components of all keys)
  for (int i = tid; i < Pc; i += 256) { int k = ckey[i]; cflag[k & 1023] = 1; cflag[k >> 10] = 1; }
  for (int i = tid; i < Px; i += 256) { int k = xkey[i]; cflag[k & 1023] = 1; cflag[k >> 10] = 1; }
  __syncthreads();
  for (int c = tid; c < 513; c += 256) {
    if (cflag[c]) {
      int idx = atomicAdd(&npp[2], 1);   // provably <= 63 (31+31+zero)
      clist[idx] = c;
      cflag[c] = idx;                    // cflag becomes cmap
    }
  }
  __syncthreads();
  int nc = npp[2];
  // rewrite keys to table indices; build encode table rows concurrently
  for (int i = tid; i < Pc; i += 256) { int k = ckey[i]; ckey[i] = cflag[k & 1023] | (cflag[k >> 10] << 10); }
  for (int i = tid; i < Px; i += 256) { int k = xkey[i]; xkey[i] = cflag[k & 1023] | (cflag[k >> 10] << 10); }

  // ---- per-block encode table rows in LDS (hash region now dead) ----
  // T(c)[g] = b2[g] + sum_f relu(c*w1[f]+b1[f]) * w2[f][g]
  for (int i = ty; i < nc; i += 4) {
    float c = (float)clist[i];
    fbF[ty * 64 + tx] = fmaxf(c * w1v + b1v, 0.f);         // wave-local h row
    float acc = b2v;
    const float4* h4 = (const float4*)&fbF[ty * 64];
#pragma unroll
    for (int q = 0; q < 16; ++q) {
      float4 hv = h4[q];
      acc += hv.x * wcA[4 * q] + hv.y * wcA[4 * q + 1] + hv.z * wcA[4 * q + 2] + hv.w * wcA[4 * q + 3];
    }
    tabL[i * 64 + tx] = acc;
  }
  // load Wk / Wv columns while table settles
#pragma unroll
  for (int f = 0; f < 64; ++f) { wcA[f] = Wk[f * 64 + tx]; wcB[f] = Wv[f * 64 + tx]; }
  float macc[16];
#pragma unroll
  for (int e = 0; e < 16; ++e) macc[e] = 0.f;
  float sacc = 0.f;
  __syncthreads();   // tabL + rewritten keys ready; hist region dead -> pool

  // ---- Phase A: M[d][e] = sum_j n_j exp(k_j[d]) v_j[e] / colsum ----
  float* pA = poolF;          // 32 x 64
  float* vA = poolF + 2048;   // 32 x 64
  for (int j0 = 0; j0 < Pc; j0 += 32) {
    int cN = min(32, Pc - j0);
    for (int j = ty; j < cN; j += 4) {
      int key = ckey[j0 + j];
      int ia = key & 1023, ib = key >> 10;
      fbF[ty * 64 + tx] = tabL[ia * 64 + tx] + tabL[ib * 64 + tx];  // wave-local
      float kr = 0.f, vr = 0.f;
      const float4* fb4 = (const float4*)&fbF[ty * 64];
#pragma unroll
      for (int q = 0; q < 16; ++q) {
        float4 fv = fb4[q];
        kr += fv.x * wcA[4 * q] + fv.y * wcA[4 * q + 1] + fv.z * wcA[4 * q + 2] + fv.w * wcA[4 * q + 3];
        vr += fv.x * wcB[4 * q] + fv.y * wcB[4 * q + 1] + fv.z * wcB[4 * q + 2] + fv.w * wcB[4 * q + 3];
      }
      float p = __expf(kr) * (float)cmult[j0 + j];  // |kr| ~ O(10): safe fp32
      sacc += p;
      pA[j * 64 + tx] = p;
      vA[j * 64 + tx] = vr;
    }
    if (j0 + 32 >= Pc) fbF[512 + ty * 64 + tx] = sacc;  // fold sacc barrier
    __syncthreads();
    // thread (tx,ty) owns M[d=tx][e0..e0+15]
    for (int jj = 0; jj < cN; ++jj) {
      float pg = pA[jj * 64 + tx];
      const float4* vb4 = (const float4*)&vA[jj * 64 + e0];
#pragma unroll
      for (int q = 0; q < 4; ++q) {
        float4 vv = vb4[q];
        macc[4 * q]     += pg * vv.x; macc[4 * q + 1] += pg * vv.y;
        macc[4 * q + 2] += pg * vv.z; macc[4 * q + 3] += pg * vv.w;
      }
    }
    __syncthreads();
  }
  float inv = 1.f / (fbF[512 + tx] + fbF[576 + tx] + fbF[640 + tx] + fbF[704 + tx]);
  // MT[f][d] = M_hat[d][f] = M[d][f] * inv[d]   (alive through Phase B)
#pragma unroll
  for (int e = 0; e < 16; ++e) Mg[(e0 + e) * 68 + tx] = macc[e] * inv;
  // Wq + Wo columns into registers (wcA/wcB dead after Phase A)
#pragma unroll
  for (int f = 0; f < 64; ++f) { wcA[f] = Wq[f * 64 + tx]; wcB[f] = Wo[f * 64 + tx]; }
  float bov = bo[tx], lg = lng[tx], lb = lnb[tx];
  __syncthreads();   // MT visible

  // ---- Phase B: per distinct x pair -> output row; chunked scatter ----
  // at = (qh . M_hat) . Wo  -- two broadcast-dots.
  for (int i0 = 0; i0 < Px; i0 += 64) {
    int cN = min(64, Px - i0);
    for (int jj = ty; jj < cN; jj += 4) {
      int key = xkey[i0 + jj];
      int ia = key & 1023, ib = key >> 10;
      float fv = tabL[ia * 64 + tx] + tabL[ib * 64 + tx];
      fbF[ty * 64 + tx] = fv;
      float qr = 0.f;
      const float4* fb4 = (const float4*)&fbF[ty * 64];
#pragma unroll
      for (int q = 0; q < 16; ++q) {
        float4 f4v = fb4[q];
        qr += f4v.x * wcA[4 * q] + f4v.y * wcA[4 * q + 1] + f4v.z * wcA[4 * q + 2] + f4v.w * wcA[4 * q + 3];
      }
      float p = __expf(qr);
      float sum = p;
#pragma unroll
      for (int off = 32; off >= 1; off >>= 1) sum += __shfl_xor(sum, off, 64);
      float qh = p / sum * 0.125f;   // softmax * F^-0.5
      fbF[256 + ty * 64 + tx] = qh;
      // stage 1: t[f=tx] = sum_d qh[d] * MT[tx][d]   (stride-68 b128, clean)
      float t = 0.f;
      const float4* qb4 = (const float4*)&fbF[256 + ty * 64];
      const float4* mt4 = (const float4*)&Mg[tx * 68];
#pragma unroll
      for (int q = 0; q < 16; ++q) {
        float4 qv = qb4[q];
        float4 mv = mt4[q];
        t += qv.x * mv.x + qv.y * mv.y + qv.z * mv.z + qv.w * mv.w;
      }
      fbF[512 + ty * 64 + tx] = t;   // sred region free in Phase B
      // stage 2: at[o=tx] = sum_f t[f] * Wo[f][tx]
      float at = 0.f;
      const float4* tb4 = (const float4*)&fbF[512 + ty * 64];
#pragma unroll
      for (int q = 0; q < 16; ++q) {
        float4 tv = tb4[q];
        at += tv.x * wcB[4 * q] + tv.y * wcB[4 * q + 1] + tv.z * wcB[4 * q + 2] + tv.w * wcB[4 * q + 3];
      }
      float r = fv + at + bov;
      float mu = r;
#pragma unroll
      for (int off = 32; off >= 1; off >>= 1) mu += __shfl_xor(mu, off, 64);
      mu *= (1.f / 64.f);
      float dv = r - mu;
      float var = dv * dv;
#pragma unroll
      for (int off = 32; off >= 1; off >>= 1) var += __shfl_xor(var, off, 64);
      var *= (1.f / 64.f);
      poolF[jj * 64 + tx] = dv * rsqrtf(var + 1e-5f) * lg + lb;
    }
    __syncthreads();
    const nfloat4* w4 = (const nfloat4*)poolF;
    nfloat4* out4 = (nfloat4*)(out + (size_t)(dir * BB + b) * (LL * 64));
    for (int idx = tid; idx < 512 * 16; idx += 256) {
      int l = idx >> 4, q = idx & 15;
      int pid = pidxl[l];
      if (pid >= i0 && pid < i0 + cN)
        __builtin_nontemporal_store(w4[(pid - i0) * 16 + q], &out4[l * 16 + q]);
    }
    __syncthreads();
  }
}

extern "C" void kernel_launch(void* const* d_in, const int* in_sizes, int n_in,
                              void* d_out, int out_size, void* d_ws, size_t ws_size,
                              hipStream_t stream) {
  const int* src  = (const int*)d_in[0];
  const int* dst  = (const int*)d_in[1];
  const float* w1 = (const float*)d_in[2];
  const float* b1 = (const float*)d_in[3];
  const float* w2 = (const float*)d_in[4];
  const float* b2 = (const float*)d_in[5];
  const float* Wq = (const float*)d_in[6];
  const float* Wk = (const float*)d_in[7];
  const float* Wv = (const float*)d_in[8];
  const float* Wo = (const float*)d_in[9];
  const float* bo = (const float*)d_in[10];
  const float* lng = (const float*)d_in[11];
  const float* lnb = (const float*)d_in[12];
  float* out = (float*)d_out;

  k_all<<<dim3(512), dim3(256), 0, stream>>>(src, dst, w1, b1, w2, b2,
                                             Wq, Wk, Wv, Wo, bo, lng, lnb, out);
}